// Round 5
// baseline (3257.316 us; speedup 1.0000x reference)
//
#include <hip/hip_runtime.h>
#include <math.h>

// Problem constants
#define BB 64
#define LL 24
#define DD 512
#define GG 2560        // 5*H
#define NSTEP 23       // LL-1
#define KS 4           // k-chunks in phase-B a/b GEMM (K=512 -> 4x128)
#define NBLK 256       // cooperative grid size (1 block/CU -- proven resident in R2)
#define NTASK 320      // 80 n-tiles (NT=64) x KS k-chunks

__device__ __forceinline__ float sigm(float x) { return 1.0f / (1.0f + __expf(-x)); }

// ---------------------------------------------------------------------------
// Slot-array grid barrier. Block j (j>0) release-stores epoch to slots[j] and
// spins on gen. Block 0 wave 0 polls all slots (acquire), then release-stores
// gen. Monotone epochs -> no reset -> no counter races. slots[0]=INT_MAX.
// grid.sync() measured ~37us (R2); this targets ~1us.
// ---------------------------------------------------------------------------
__device__ __forceinline__ void gbar(int* __restrict__ slots, int* __restrict__ gen,
                                     int target, int nblk) {
    (void)nblk;
    __syncthreads();
    if (blockIdx.x == 0) {
        if (threadIdx.x < 64) {
            bool alldone = false;
            while (!alldone) {
                bool ok = true;
#pragma unroll
                for (int j = 0; j < NBLK / 64; ++j) {
                    int v = __hip_atomic_load(&slots[threadIdx.x + j * 64], __ATOMIC_ACQUIRE,
                                              __HIP_MEMORY_SCOPE_AGENT);
                    ok &= (v >= target);
                }
                alldone = __all(ok);
                if (!alldone) __builtin_amdgcn_s_sleep(2);
            }
        }
        __syncthreads();
        if (threadIdx.x == 0) {
            __threadfence();
            __hip_atomic_store(gen, target, __ATOMIC_RELEASE, __HIP_MEMORY_SCOPE_AGENT);
        }
        __syncthreads();
    } else {
        if (threadIdx.x == 0) {
            __threadfence();
            __hip_atomic_store(&slots[blockIdx.x], target, __ATOMIC_RELEASE,
                               __HIP_MEMORY_SCOPE_AGENT);
            while (__hip_atomic_load(gen, __ATOMIC_ACQUIRE, __HIP_MEMORY_SCOPE_AGENT) < target) {
                __builtin_amdgcn_s_sleep(2);
            }
            __threadfence();
        }
        __syncthreads();
    }
}

// ---------------------------------------------------------------------------
// init: zero barrier state. slots[0] = INT_MAX (block 0 never stores its slot).
// ---------------------------------------------------------------------------
__global__ void init_k(int* __restrict__ bar) {
    int tid = threadIdx.x;
    if (tid < NBLK) bar[tid] = (tid == 0) ? 0x7FFFFFFF : 0;
    if (tid == 0) bar[NBLK] = 0;  // gen
}

// ---------------------------------------------------------------------------
// Big fp32 GEMM, conflict-free microtile (unchanged from R2 — verified).
// ---------------------------------------------------------------------------
template <int MODE>
__global__ __launch_bounds__(256) void gemm_big(const float* __restrict__ A,
                                                const float* __restrict__ Wt,
                                                const float* __restrict__ bias,
                                                float* __restrict__ O0,
                                                float* __restrict__ O1) {
    __shared__ float As[16][132];
    __shared__ float Bs[16][132];
    const int tid = threadIdx.x;
    const int n0 = blockIdx.x * 128;
    const int m0 = blockIdx.y * 128;
    const int tn = tid & 15;
    const int tm = tid >> 4;

    float acc[8][8];
#pragma unroll
    for (int y = 0; y < 8; ++y)
#pragma unroll
        for (int x = 0; x < 8; ++x) acc[y][x] = 0.f;

    for (int kt = 0; kt < 512; kt += 16) {
#pragma unroll
        for (int ii = 0; ii < 2; ++ii) {
            int idx = tid + ii * 256;
            int r = idx >> 2, c4 = idx & 3;
            float4 v = *(const float4*)(A + (size_t)(m0 + r) * DD + kt + c4 * 4);
            As[c4 * 4 + 0][r] = v.x;
            As[c4 * 4 + 1][r] = v.y;
            As[c4 * 4 + 2][r] = v.z;
            As[c4 * 4 + 3][r] = v.w;
        }
#pragma unroll
        for (int ii = 0; ii < 2; ++ii) {
            int idx = tid + ii * 256;
            int r = idx >> 2, c4 = idx & 3;
            int n = n0 + r;
            const float* wrow;
            if constexpr (MODE == 0) {
                wrow = Wt + (size_t)n * DD;
            } else {
                wrow = (n < GG) ? (Wt + (size_t)n * (2 * DD))
                                : (Wt + (size_t)(n - GG) * (2 * DD) + DD);
            }
            float4 v = *(const float4*)(wrow + kt + c4 * 4);
            Bs[c4 * 4 + 0][r] = v.x;
            Bs[c4 * 4 + 1][r] = v.y;
            Bs[c4 * 4 + 2][r] = v.z;
            Bs[c4 * 4 + 3][r] = v.w;
        }
        __syncthreads();
#pragma unroll
        for (int k = 0; k < 16; ++k) {
            float4 a0 = *(const float4*)&As[k][tm * 8];
            float4 a1 = *(const float4*)&As[k][tm * 8 + 4];
            float4 b0 = *(const float4*)&Bs[k][tn * 4];
            float4 b1 = *(const float4*)&Bs[k][64 + tn * 4];
            float av[8] = {a0.x, a0.y, a0.z, a0.w, a1.x, a1.y, a1.z, a1.w};
            float bv[8] = {b0.x, b0.y, b0.z, b0.w, b1.x, b1.y, b1.z, b1.w};
#pragma unroll
            for (int y = 0; y < 8; ++y)
#pragma unroll
                for (int x = 0; x < 8; ++x) acc[y][x] += av[y] * bv[x];
        }
        __syncthreads();
    }

#pragma unroll
    for (int y = 0; y < 8; ++y) {
        const int m = m0 + tm * 8 + y;
#pragma unroll
        for (int g = 0; g < 2; ++g) {
            int n = n0 + g * 64 + tn * 4;
            float4 v;
            v.x = acc[y][g * 4 + 0];
            v.y = acc[y][g * 4 + 1];
            v.z = acc[y][g * 4 + 2];
            v.w = acc[y][g * 4 + 3];
            float* dst;
            if constexpr (MODE == 0) {
                v.x += bias[n + 0];
                v.y += bias[n + 1];
                v.z += bias[n + 2];
                v.w += bias[n + 3];
                dst = (n < DD) ? (O0 + (size_t)m * DD + n) : (O1 + (size_t)m * DD + (n - DD));
            } else {
                dst = (n < GG) ? (O0 + (size_t)m * GG + n) : (O1 + (size_t)m * GG + (n - GG));
            }
            *(float4*)dst = v;
        }
    }
}

// ---------------------------------------------------------------------------
// half-block (128-lane) candidate scorer: partial q.new_h, wave-reduced.
// Wave sum lands on lanes with (tid&63)==0.
// ---------------------------------------------------------------------------
__device__ __forceinline__ float half_dot(const float* __restrict__ ar,
                                          const float* __restrict__ br,
                                          const float* __restrict__ cb,
                                          const float* __restrict__ cl,
                                          const float* __restrict__ cr,
                                          const float* __restrict__ q, int lane) {
    float part = 0.f;
#pragma unroll
    for (int d = lane; d < DD; d += 128) {
        float gi = ar[d] + br[d] + cb[d];
        float gfl = ar[DD + d] + br[DD + d] + cb[DD + d];
        float gfr = ar[2 * DD + d] + br[2 * DD + d] + cb[2 * DD + d];
        float gu = ar[3 * DD + d] + br[3 * DD + d] + cb[3 * DD + d];
        float go = ar[4 * DD + d] + br[4 * DD + d] + cb[4 * DD + d];
        float nc = cl[d] * sigm(gfl + 1.f) + cr[d] * sigm(gfr + 1.f) + tanhf(gu) * sigm(gi);
        part += sigm(go) * tanhf(nc) * q[d];
    }
#pragma unroll
    for (int off = 32; off; off >>= 1) part += __shfl_down(part, off);
    return part;
}

// ---------------------------------------------------------------------------
// Persistent kernel: initial scoring + all 23 merge steps.
// Blocks 0..63 own batch state (phase A); all 256 blocks do phase-B GEMM
// (320 tile-tasks: pass 0 = all blocks, pass 1 = blocks 192..255).
// ---------------------------------------------------------------------------
__global__ __launch_bounds__(256, 2) void loop_k(
    const int* __restrict__ length, float* __restrict__ hbuf, float* __restrict__ cbuf,
    float* __restrict__ acache, float* __restrict__ bcache, float* __restrict__ part,
    float* __restrict__ scores_g, int* __restrict__ msel, const float* __restrict__ comp_W,
    const float* __restrict__ compb, const float* __restrict__ q, float* __restrict__ out,
    int* __restrict__ bar) {
    __shared__ float As[32][68];
    __shared__ float Bs[32][68];
    __shared__ float red_s[4];
    __shared__ float sc_l[32];
    __shared__ int seq_l[32];
    __shared__ int k_sh;

    const int tid = threadIdx.x;
    const int bid = blockIdx.x;
    const int b = bid;
    const bool amA = bid < BB;
    const int half = tid >> 7;
    const int lane7 = tid & 127;

    int* slots = bar;
    int* gen = bar + NBLK;
    int ep = 0;

    // uniform max length (lengths in [12,24])
    int maxlen = 0;
    for (int j = 0; j < BB; ++j) maxlen = max(maxlen, length[j]);
    int lenb = 0, kp = 0, sml = 0;
    if (amA) lenb = length[b];

    // ---- pre-phase: all 23x64 initial candidate scores (512 half-blocks) ----
    for (int it = 0; it < 3; ++it) {
        int c = it * (2 * NBLK) + bid * 2 + half;
        bool valid = c < BB * NSTEP;
        float w = 0.f;
        if (valid) {
            int cb_ = c / NSTEP, cp = c % NSTEP;
            w = half_dot(acache + (size_t)(cb_ * LL + cp) * GG,
                         bcache + (size_t)(cb_ * LL + cp + 1) * GG, compb,
                         cbuf + (size_t)(cb_ * LL + cp) * DD,
                         cbuf + (size_t)(cb_ * LL + cp + 1) * DD, q, lane7);
        }
        if ((tid & 63) == 0) red_s[tid >> 6] = w;
        __syncthreads();
        if ((tid == 0 || tid == 128) && valid) {
            int base = (tid >> 6);
            scores_g[c] = red_s[base] + red_s[base + 1];
        }
        __syncthreads();
    }
    gbar(slots, gen, ++ep, NBLK);

    if (amA) {
        if (tid < NSTEP) sc_l[tid] = scores_g[b * NSTEP + tid];
        if (tid < LL) seq_l[tid] = tid;
    }
    __syncthreads();

    const int imax = min(NSTEP, maxlen - 1);  // merge steps 0..imax-1
    for (int i = 0; i < imax; ++i) {
        // ---------------- phase A (blocks 0..63) ----------------
        if (amA) {
            const int ncand = NSTEP - i;
            if (i > 0 && i < lenb) {
                // reduce k-split partials of last-merged row into a/b caches
                const size_t row = (size_t)(b * LL + sml);
                const float4* p0 = (const float4*)(part + (size_t)(0 * BB + b) * (2 * GG));
                const float4* p1 = (const float4*)(part + (size_t)(1 * BB + b) * (2 * GG));
                const float4* p2 = (const float4*)(part + (size_t)(2 * BB + b) * (2 * GG));
                const float4* p3 = (const float4*)(part + (size_t)(3 * BB + b) * (2 * GG));
                float4* arow = (float4*)(acache + row * GG);
                float4* brow = (float4*)(bcache + row * GG);
                for (int n4 = tid; n4 < (2 * GG) / 4; n4 += 256) {
                    float4 va = p0[n4], vb = p1[n4], vc = p2[n4], vd = p3[n4];
                    float4 s;
                    s.x = va.x + vb.x + vc.x + vd.x;
                    s.y = va.y + vb.y + vc.y + vd.y;
                    s.z = va.z + vb.z + vc.z + vd.z;
                    s.w = va.w + vb.w + vc.w + vd.w;
                    if (n4 < GG / 4) arow[n4] = s;
                    else brow[n4 - GG / 4] = s;
                }
                __syncthreads();
                // rescore the <=2 affected candidates (both halves concurrent)
                int p = (tid < 128) ? (kp - 1) : kp;
                bool valid = (p >= 0) && (p < ncand);
                float w = 0.f;
                if (valid) {
                    int sl = seq_l[p], sr = seq_l[p + 1];
                    w = half_dot(acache + (size_t)(b * LL + sl) * GG,
                                 bcache + (size_t)(b * LL + sr) * GG, compb,
                                 cbuf + (size_t)(b * LL + sl) * DD,
                                 cbuf + (size_t)(b * LL + sr) * DD, q, lane7);
                }
                if ((tid & 63) == 0) red_s[tid >> 6] = w;
                __syncthreads();
                if (tid == 0) {
                    if (kp - 1 >= 0) sc_l[kp - 1] = red_s[0] + red_s[1];
                    if (kp < ncand) sc_l[kp] = red_s[2] + red_s[3];
                }
                __syncthreads();
            }
            if (i + 1 < lenb) {
                if (tid == 0) {
                    const int vmax = lenb - i - 2;
                    int k = 0;
                    float best = sc_l[0];
                    for (int pp = 1; pp <= vmax; ++pp)
                        if (sc_l[pp] > best) { best = sc_l[pp]; k = pp; }
                    k_sh = k;
                }
                __syncthreads();
                const int k = k_sh;
                const int sl = seq_l[k], sr = seq_l[k + 1];
                const float* ar = acache + (size_t)(b * LL + sl) * GG;
                const float* br = bcache + (size_t)(b * LL + sr) * GG;
                const float* cl = cbuf + (size_t)(b * LL + sl) * DD;
                const float* cr = cbuf + (size_t)(b * LL + sr) * DD;
                float* hw = hbuf + (size_t)(b * LL + sl) * DD;
                float* cw = cbuf + (size_t)(b * LL + sl) * DD;
#pragma unroll
                for (int d = tid; d < DD; d += 256) {
                    float gi = ar[d] + br[d] + compb[d];
                    float gfl = ar[DD + d] + br[DD + d] + compb[DD + d];
                    float gfr = ar[2 * DD + d] + br[2 * DD + d] + compb[2 * DD + d];
                    float gu = ar[3 * DD + d] + br[3 * DD + d] + compb[3 * DD + d];
                    float go = ar[4 * DD + d] + br[4 * DD + d] + compb[4 * DD + d];
                    float nc = cl[d] * sigm(gfl + 1.f) + cr[d] * sigm(gfr + 1.f) +
                               tanhf(gu) * sigm(gi);
                    hw[d] = sigm(go) * tanhf(nc);
                    cw[d] = nc;
                }
                float sv = (tid + 1 < ncand) ? sc_l[tid + 1] : 0.f;
                int qv = (tid + 1 < LL - i) ? seq_l[tid + 1] : 0;
                __syncthreads();
                if (tid >= k + 1 && tid <= ncand - 2) sc_l[tid] = sv;
                if (tid >= k + 1 && tid <= LL - i - 2) seq_l[tid] = qv;
                if (tid == 0) msel[b] = sl;
                kp = k;
                sml = sl;
            }
        }
        // ---------------- phase B (320 tile-tasks on 256 blocks) -------------
        if (i < imax - 1) {
            gbar(slots, gen, ++ep, NBLK);
#pragma unroll 1
            for (int pass = 0; pass < 2; ++pass) {
                if (pass == 1 && bid < 192) break;
                const int t = (pass == 0) ? bid : (256 + bid - 192);
                const int ntile = t % 80;
                const int kb = t / 80;
                const int k0 = kb * 128;
                const int tn = tid & 15, tm = tid >> 4;
                float acc[4][4];
#pragma unroll
                for (int y = 0; y < 4; ++y)
#pragma unroll
                    for (int x = 0; x < 4; ++x) acc[y][x] = 0.f;
                for (int kt = 0; kt < 128; kt += 32) {
                    const int kbase = k0 + kt;
#pragma unroll
                    for (int ii = 0; ii < 2; ++ii) {  // A: 64 batch-rows x 32 k
                        int idx = tid + ii * 256;
                        int r = idx >> 3, c4 = idx & 7;
                        const float* arow = hbuf + ((size_t)r * LL + msel[r]) * DD;
                        float4 v = *(const float4*)(arow + kbase + c4 * 4);
                        As[c4 * 4 + 0][r] = v.x;
                        As[c4 * 4 + 1][r] = v.y;
                        As[c4 * 4 + 2][r] = v.z;
                        As[c4 * 4 + 3][r] = v.w;
                    }
#pragma unroll
                    for (int ii = 0; ii < 2; ++ii) {  // B: 64 W-rows x 32 k
                        int idx = tid + ii * 256;
                        int r = idx >> 3, c4 = idx & 7;
                        int n = ntile * 64 + r;
                        const float* wrow = (n < GG)
                                                ? (comp_W + (size_t)n * (2 * DD))
                                                : (comp_W + (size_t)(n - GG) * (2 * DD) + DD);
                        float4 v = *(const float4*)(wrow + kbase + c4 * 4);
                        Bs[c4 * 4 + 0][r] = v.x;
                        Bs[c4 * 4 + 1][r] = v.y;
                        Bs[c4 * 4 + 2][r] = v.z;
                        Bs[c4 * 4 + 3][r] = v.w;
                    }
                    __syncthreads();
#pragma unroll
                    for (int k = 0; k < 32; ++k) {
                        float4 a = *(const float4*)&As[k][tm * 4];
                        float4 w = *(const float4*)&Bs[k][tn * 4];
                        float av[4] = {a.x, a.y, a.z, a.w};
                        float wv[4] = {w.x, w.y, w.z, w.w};
#pragma unroll
                        for (int y = 0; y < 4; ++y)
#pragma unroll
                            for (int x = 0; x < 4; ++x) acc[y][x] += av[y] * wv[x];
                    }
                    __syncthreads();
                }
#pragma unroll
                for (int y = 0; y < 4; ++y) {
                    int m = tm * 4 + y;
                    float4 v;
                    v.x = acc[y][0];
                    v.y = acc[y][1];
                    v.z = acc[y][2];
                    v.w = acc[y][3];
                    *(float4*)(part + (size_t)(kb * BB + m) * (2 * GG) + ntile * 64 + tn * 4) = v;
                }
            }
            gbar(slots, gen, ++ep, NBLK);
        }
    }

    if (amA) {
        __syncthreads();
        const int s0 = seq_l[0];  // slot 0 never shifts
        for (int d = tid; d < DD; d += 256)
            out[b * DD + d] = hbuf[(size_t)(b * LL + s0) * DD + d];
    }
}

// ---------------------------------------------------------------------------
extern "C" void kernel_launch(void* const* d_in, const int* in_sizes, int n_in, void* d_out,
                              int out_size, void* d_ws, size_t ws_size, hipStream_t stream) {
    const float* inp = (const float*)d_in[0];
    const int* length = (const int*)d_in[1];
    const float* word_W = (const float*)d_in[2];
    const float* word_b = (const float*)d_in[3];
    const float* comp_W = (const float*)d_in[4];
    const float* comp_b = (const float*)d_in[5];
    const float* comp_q = (const float*)d_in[6];
    float* out = (float*)d_out;

    float* ws = (float*)d_ws;
    size_t off = 0;
    float* hbuf = ws + off;   off += (size_t)BB * LL * DD;
    float* cbuf = ws + off;   off += (size_t)BB * LL * DD;
    float* acache = ws + off; off += (size_t)BB * LL * GG;
    float* bcache = ws + off; off += (size_t)BB * LL * GG;
    float* part = ws + off;   off += (size_t)KS * BB * 2 * GG;
    float* scores = ws + off; off += 2048;
    int* msel = (int*)(ws + off); off += 64;
    int* bar = (int*)(ws + off);  off += NBLK + 64;
    (void)ws_size; (void)in_sizes; (void)n_in; (void)out_size;

    // zero barrier state (ws is poisoned 0xAA before every call)
    init_k<<<1, 256, 0, stream>>>(bar);

    // word projection: h,c = split(inp @ word_W.T + word_b)
    gemm_big<0><<<dim3(8, 12), 256, 0, stream>>>(inp, word_W, word_b, hbuf, cbuf);

    // a/b caches for all 1536 items
    gemm_big<1><<<dim3(40, 12), 256, 0, stream>>>(hbuf, comp_W, nullptr, acache, bcache);

    // persistent kernel: initial scores + all merge steps
    const int* a0 = length;
    float* a1 = hbuf; float* a2 = cbuf; float* a3 = acache; float* a4 = bcache;
    float* a5 = part; float* a6 = scores; int* a7 = msel;
    const float* a8 = comp_W; const float* a9 = comp_b; const float* a10 = comp_q;
    float* a11 = out; int* a12 = bar;
    void* args[] = {&a0, &a1, &a2, &a3, &a4, &a5, &a6, &a7, &a8, &a9, &a10, &a11, &a12};
    hipError_t err = hipLaunchCooperativeKernel(reinterpret_cast<void*>(loop_k), dim3(NBLK),
                                                dim3(256), args, 0, stream);
    (void)err;
}

// Round 6
// 1021.782 us; speedup vs baseline: 3.1879x; 3.1879x over previous
//
#include <hip/hip_runtime.h>
#include <math.h>

// Problem constants
#define BB 64
#define LL 24
#define DD 512
#define GG 2560        // 5*H
#define NSTEP 23       // LL-1
#define KS 4           // k-chunks in phase-B a/b GEMM (K=512 -> 4x128)
#define NBLK 256       // cooperative grid size (1 block/CU -- proven resident in R2)

__device__ __forceinline__ float sigm(float x) { return 1.0f / (1.0f + __expf(-x)); }

// ---------------------------------------------------------------------------
// Coherent (agent-scope sc1) access helpers. RELAXED ordering: no buffer_inv /
// buffer_wbl2 cache maintenance (the R5 killer). Cross-XCD visibility comes
// from the sc1 bit on each access (coherent point), ordering from the
// s_waitcnt vmcnt(0) that __syncthreads emits + explicit drains.
// ---------------------------------------------------------------------------
__device__ __forceinline__ void stf2(float* p, float a, float b) {
    union { float f[2]; unsigned long long u; } x;
    x.f[0] = a; x.f[1] = b;
    __hip_atomic_store((unsigned long long*)p, x.u, __ATOMIC_RELAXED, __HIP_MEMORY_SCOPE_AGENT);
}
__device__ __forceinline__ float2 ldf2(const float* p) {
    union { float f[2]; unsigned long long u; } x;
    x.u = __hip_atomic_load((unsigned long long*)p, __ATOMIC_RELAXED, __HIP_MEMORY_SCOPE_AGENT);
    return make_float2(x.f[0], x.f[1]);
}
__device__ __forceinline__ void stf(float* p, float v) {
    __hip_atomic_store(p, v, __ATOMIC_RELAXED, __HIP_MEMORY_SCOPE_AGENT);
}
__device__ __forceinline__ float ldf(const float* p) {
    return __hip_atomic_load((float*)p, __ATOMIC_RELAXED, __HIP_MEMORY_SCOPE_AGENT);
}
__device__ __forceinline__ void sti(int* p, int v) {
    __hip_atomic_store(p, v, __ATOMIC_RELAXED, __HIP_MEMORY_SCOPE_AGENT);
}
__device__ __forceinline__ int ldi(const int* p) {
    return __hip_atomic_load((int*)p, __ATOMIC_RELAXED, __HIP_MEMORY_SCOPE_AGENT);
}
__device__ __forceinline__ void drain_stores() {
    asm volatile("s_waitcnt vmcnt(0)" ::: "memory");
}

// ---------------------------------------------------------------------------
// Slot-array grid barrier with RELAXED sc1 spins (no cache maintenance).
// Block j>0: drain, store epoch to slots[j], spin on gen. Block 0 wave 0:
// poll all slots, drain, store gen. Monotone epochs -> no reset.
// ---------------------------------------------------------------------------
__device__ __forceinline__ void gbar(int* __restrict__ slots, int* __restrict__ gen,
                                     int target) {
    __syncthreads();  // compiler emits s_waitcnt vmcnt(0) before s_barrier: drains all waves
    if (blockIdx.x == 0) {
        if (threadIdx.x < 64) {
            bool alldone = false;
            while (!alldone) {
                bool ok = true;
#pragma unroll
                for (int j = 0; j < NBLK / 64; ++j)
                    ok &= (ldi(&slots[threadIdx.x + j * 64]) >= target);
                alldone = __all(ok);
                if (!alldone) __builtin_amdgcn_s_sleep(2);
            }
        }
        __syncthreads();
        if (threadIdx.x == 0) { drain_stores(); sti(gen, target); }
    } else {
        if (threadIdx.x == 0) {
            drain_stores();
            sti(&slots[blockIdx.x], target);
            while (ldi(gen) < target) __builtin_amdgcn_s_sleep(2);
        }
    }
    __syncthreads();
}

// ---------------------------------------------------------------------------
// init: barrier state. slots[0] = INT_MAX (block 0 never stores its slot).
// ---------------------------------------------------------------------------
__global__ void init_k(int* __restrict__ bar) {
    int tid = threadIdx.x;
    if (tid < NBLK) bar[tid] = (tid == 0) ? 0x7FFFFFFF : 0;
    if (tid == 0) bar[NBLK] = 0;  // gen
}

// ---------------------------------------------------------------------------
// Big fp32 GEMM, conflict-free microtile (unchanged — verified R2/R5).
// ---------------------------------------------------------------------------
template <int MODE>
__global__ __launch_bounds__(256) void gemm_big(const float* __restrict__ A,
                                                const float* __restrict__ Wt,
                                                const float* __restrict__ bias,
                                                float* __restrict__ O0,
                                                float* __restrict__ O1) {
    __shared__ float As[16][132];
    __shared__ float Bs[16][132];
    const int tid = threadIdx.x;
    const int n0 = blockIdx.x * 128;
    const int m0 = blockIdx.y * 128;
    const int tn = tid & 15;
    const int tm = tid >> 4;

    float acc[8][8];
#pragma unroll
    for (int y = 0; y < 8; ++y)
#pragma unroll
        for (int x = 0; x < 8; ++x) acc[y][x] = 0.f;

    for (int kt = 0; kt < 512; kt += 16) {
#pragma unroll
        for (int ii = 0; ii < 2; ++ii) {
            int idx = tid + ii * 256;
            int r = idx >> 2, c4 = idx & 3;
            float4 v = *(const float4*)(A + (size_t)(m0 + r) * DD + kt + c4 * 4);
            As[c4 * 4 + 0][r] = v.x;
            As[c4 * 4 + 1][r] = v.y;
            As[c4 * 4 + 2][r] = v.z;
            As[c4 * 4 + 3][r] = v.w;
        }
#pragma unroll
        for (int ii = 0; ii < 2; ++ii) {
            int idx = tid + ii * 256;
            int r = idx >> 2, c4 = idx & 3;
            int n = n0 + r;
            const float* wrow;
            if constexpr (MODE == 0) {
                wrow = Wt + (size_t)n * DD;
            } else {
                wrow = (n < GG) ? (Wt + (size_t)n * (2 * DD))
                                : (Wt + (size_t)(n - GG) * (2 * DD) + DD);
            }
            float4 v = *(const float4*)(wrow + kt + c4 * 4);
            Bs[c4 * 4 + 0][r] = v.x;
            Bs[c4 * 4 + 1][r] = v.y;
            Bs[c4 * 4 + 2][r] = v.z;
            Bs[c4 * 4 + 3][r] = v.w;
        }
        __syncthreads();
#pragma unroll
        for (int k = 0; k < 16; ++k) {
            float4 a0 = *(const float4*)&As[k][tm * 8];
            float4 a1 = *(const float4*)&As[k][tm * 8 + 4];
            float4 b0 = *(const float4*)&Bs[k][tn * 4];
            float4 b1 = *(const float4*)&Bs[k][64 + tn * 4];
            float av[8] = {a0.x, a0.y, a0.z, a0.w, a1.x, a1.y, a1.z, a1.w};
            float bv[8] = {b0.x, b0.y, b0.z, b0.w, b1.x, b1.y, b1.z, b1.w};
#pragma unroll
            for (int y = 0; y < 8; ++y)
#pragma unroll
                for (int x = 0; x < 8; ++x) acc[y][x] += av[y] * bv[x];
        }
        __syncthreads();
    }

#pragma unroll
    for (int y = 0; y < 8; ++y) {
        const int m = m0 + tm * 8 + y;
#pragma unroll
        for (int g = 0; g < 2; ++g) {
            int n = n0 + g * 64 + tn * 4;
            float4 v;
            v.x = acc[y][g * 4 + 0];
            v.y = acc[y][g * 4 + 1];
            v.z = acc[y][g * 4 + 2];
            v.w = acc[y][g * 4 + 3];
            float* dst;
            if constexpr (MODE == 0) {
                v.x += bias[n + 0];
                v.y += bias[n + 1];
                v.z += bias[n + 2];
                v.w += bias[n + 3];
                dst = (n < DD) ? (O0 + (size_t)m * DD + n) : (O1 + (size_t)m * DD + (n - DD));
            } else {
                dst = (n < GG) ? (O0 + (size_t)m * GG + n) : (O1 + (size_t)m * GG + (n - GG));
            }
            *(float4*)dst = v;
        }
    }
}

// ---------------------------------------------------------------------------
// half-block (128-lane) candidate scorer (normal cached loads; operands are
// either inputs, prev-dispatch outputs, or owner-private). Wave sum lands on
// lanes with (tid&63)==0.
// ---------------------------------------------------------------------------
__device__ __forceinline__ float half_dot(const float* __restrict__ ar,
                                          const float* __restrict__ br,
                                          const float* __restrict__ cb,
                                          const float* __restrict__ cl,
                                          const float* __restrict__ cr,
                                          const float* __restrict__ q, int lane) {
    float part = 0.f;
#pragma unroll
    for (int d = lane; d < DD; d += 128) {
        float gi = ar[d] + br[d] + cb[d];
        float gfl = ar[DD + d] + br[DD + d] + cb[DD + d];
        float gfr = ar[2 * DD + d] + br[2 * DD + d] + cb[2 * DD + d];
        float gu = ar[3 * DD + d] + br[3 * DD + d] + cb[3 * DD + d];
        float go = ar[4 * DD + d] + br[4 * DD + d] + cb[4 * DD + d];
        float nc = cl[d] * sigm(gfl + 1.f) + cr[d] * sigm(gfr + 1.f) + tanhf(gu) * sigm(gi);
        part += sigm(go) * tanhf(nc) * q[d];
    }
#pragma unroll
    for (int off = 32; off; off >>= 1) part += __shfl_down(part, off);
    return part;
}

// ---------------------------------------------------------------------------
// Persistent kernel. Cross-block data flows ONLY through sc1 helpers:
//   part (phase B -> owner), hbuf merged rows (owner -> phase B, final copy),
//   msel (owner -> phase B), scores_g (pre-phase -> owner).
// Owner-private (acache/bcache reduced rows, cbuf, sc_l/seq_l): normal/cached.
// ---------------------------------------------------------------------------
__global__ __launch_bounds__(256, 2) void loop_k(
    const int* __restrict__ length, float* __restrict__ hbuf, float* __restrict__ cbuf,
    float* __restrict__ acache, float* __restrict__ bcache, float* __restrict__ part,
    float* __restrict__ scores_g, int* __restrict__ msel, const float* __restrict__ comp_W,
    const float* __restrict__ compb, const float* __restrict__ q, float* __restrict__ out,
    int* __restrict__ bar) {
    __shared__ float As[32][68];
    __shared__ float Bs[32][68];
    __shared__ float red_s[4];
    __shared__ float sc_l[32];
    __shared__ int seq_l[32];
    __shared__ int k_sh;
    __shared__ int msel_s[BB];

    const int tid = threadIdx.x;
    const int bid = blockIdx.x;
    const int b = bid;
    const bool amA = bid < BB;
    const int half = tid >> 7;
    const int lane7 = tid & 127;

    int* slots = bar;
    int* gen = bar + NBLK;
    int ep = 0;

    // uniform max length (inputs; identical across blocks)
    int maxlen = 0;
    for (int j = 0; j < BB; ++j) maxlen = max(maxlen, length[j]);
    int lenb = 0, kp = 0, sml = 0;
    if (amA) lenb = length[b];

    // ---- pre-phase: all 23x64 initial candidate scores (512 half-blocks) ----
    for (int it = 0; it < 3; ++it) {
        int c = it * (2 * NBLK) + bid * 2 + half;
        bool valid = c < BB * NSTEP;
        float w = 0.f;
        if (valid) {
            int cb_ = c / NSTEP, cp = c % NSTEP;
            w = half_dot(acache + (size_t)(cb_ * LL + cp) * GG,
                         bcache + (size_t)(cb_ * LL + cp + 1) * GG, compb,
                         cbuf + (size_t)(cb_ * LL + cp) * DD,
                         cbuf + (size_t)(cb_ * LL + cp + 1) * DD, q, lane7);
        }
        if ((tid & 63) == 0) red_s[tid >> 6] = w;
        __syncthreads();
        if ((tid == 0 || tid == 128) && valid) {
            int base = (tid >> 6);
            stf(&scores_g[c], red_s[base] + red_s[base + 1]);  // sc1: cross-block
        }
        __syncthreads();
    }
    gbar(slots, gen, ++ep);

    if (amA) {
        if (tid < NSTEP) sc_l[tid] = ldf(&scores_g[b * NSTEP + tid]);  // sc1
        if (tid < LL) seq_l[tid] = tid;
    }
    __syncthreads();

    const int imax = min(NSTEP, maxlen - 1);  // merge steps 0..imax-1
    for (int i = 0; i < imax; ++i) {
        // ---------------- phase A (blocks 0..63) ----------------
        if (amA) {
            const int ncand = NSTEP - i;
            if (i > 0 && i < lenb) {
                // reduce k-split partials (sc1 reads) into owner-private a/b rows
                const size_t row = (size_t)(b * LL + sml);
                float* arow = acache + row * GG;
                float* brow = bcache + row * GG;
                for (int n2 = tid; n2 < GG; n2 += 256) {  // GG float2 = 2*GG floats
                    float s0 = 0.f, s1 = 0.f;
#pragma unroll
                    for (int kk = 0; kk < KS; ++kk) {
                        float2 v = ldf2(part + (size_t)(kk * BB + b) * (2 * GG) + 2 * n2);
                        s0 += v.x;
                        s1 += v.y;
                    }
                    int n = 2 * n2;
                    if (n < GG) *(float2*)(arow + n) = make_float2(s0, s1);
                    else *(float2*)(brow + n - GG) = make_float2(s0, s1);
                }
                __syncthreads();
                // rescore the <=2 affected candidates (both halves concurrent)
                int p = (tid < 128) ? (kp - 1) : kp;
                bool valid = (p >= 0) && (p < ncand);
                float w = 0.f;
                if (valid) {
                    int sl = seq_l[p], sr = seq_l[p + 1];
                    w = half_dot(acache + (size_t)(b * LL + sl) * GG,
                                 bcache + (size_t)(b * LL + sr) * GG, compb,
                                 cbuf + (size_t)(b * LL + sl) * DD,
                                 cbuf + (size_t)(b * LL + sr) * DD, q, lane7);
                }
                if ((tid & 63) == 0) red_s[tid >> 6] = w;
                __syncthreads();
                if (tid == 0) {
                    if (kp - 1 >= 0) sc_l[kp - 1] = red_s[0] + red_s[1];
                    if (kp < ncand) sc_l[kp] = red_s[2] + red_s[3];
                }
                __syncthreads();
            }
            if (i + 1 < lenb) {
                if (tid == 0) {
                    const int vmax = lenb - i - 2;
                    int k = 0;
                    float best = sc_l[0];
                    for (int pp = 1; pp <= vmax; ++pp)
                        if (sc_l[pp] > best) { best = sc_l[pp]; k = pp; }
                    k_sh = k;
                }
                __syncthreads();
                const int k = k_sh;
                const int sl = seq_l[k], sr = seq_l[k + 1];
                const float* ar = acache + (size_t)(b * LL + sl) * GG;
                const float* br = bcache + (size_t)(b * LL + sr) * GG;
                const float* cl = cbuf + (size_t)(b * LL + sl) * DD;
                const float* cr = cbuf + (size_t)(b * LL + sr) * DD;
                float* hw = hbuf + (size_t)(b * LL + sl) * DD;
                float* cw = cbuf + (size_t)(b * LL + sl) * DD;
                {  // winner gates; h written sc1 (read by phase B), c owner-private
                    const int d = 2 * tid;  // 256 threads x float2 = 512
                    float nh[2], ncv[2];
#pragma unroll
                    for (int j = 0; j < 2; ++j) {
                        int dd = d + j;
                        float gi = ar[dd] + br[dd] + compb[dd];
                        float gfl = ar[DD + dd] + br[DD + dd] + compb[DD + dd];
                        float gfr = ar[2 * DD + dd] + br[2 * DD + dd] + compb[2 * DD + dd];
                        float gu = ar[3 * DD + dd] + br[3 * DD + dd] + compb[3 * DD + dd];
                        float go = ar[4 * DD + dd] + br[4 * DD + dd] + compb[4 * DD + dd];
                        float nc = cl[dd] * sigm(gfl + 1.f) + cr[dd] * sigm(gfr + 1.f) +
                                   tanhf(gu) * sigm(gi);
                        ncv[j] = nc;
                        nh[j] = sigm(go) * tanhf(nc);
                    }
                    stf2(hw + d, nh[0], nh[1]);
                    *(float2*)(cw + d) = make_float2(ncv[0], ncv[1]);
                }
                float sv = (tid + 1 < ncand) ? sc_l[tid + 1] : 0.f;
                int qv = (tid + 1 < LL - i) ? seq_l[tid + 1] : 0;
                __syncthreads();
                if (tid >= k + 1 && tid <= ncand - 2) sc_l[tid] = sv;
                if (tid >= k + 1 && tid <= LL - i - 2) seq_l[tid] = qv;
                if (tid == 0) sti(&msel[b], sl);  // sc1: read by phase B
                kp = k;
                sml = sl;
            }
        }
        // ---------------- phase B (320 tile-tasks on 256 blocks) -------------
        if (i < imax - 1) {
            gbar(slots, gen, ++ep);
            if (tid < BB) msel_s[tid] = ldi(&msel[tid]);  // sc1, staged to LDS
            __syncthreads();
#pragma unroll 1
            for (int pass = 0; pass < 2; ++pass) {
                if (pass == 1 && bid < 192) break;
                const int t = (pass == 0) ? bid : (256 + bid - 192);
                const int ntile = t % 80;
                const int kb = t / 80;
                const int k0 = kb * 128;
                const int tn = tid & 15, tm = tid >> 4;
                float acc[4][4];
#pragma unroll
                for (int y = 0; y < 4; ++y)
#pragma unroll
                    for (int x = 0; x < 4; ++x) acc[y][x] = 0.f;
                for (int kt = 0; kt < 128; kt += 32) {
                    const int kbase = k0 + kt;
#pragma unroll
                    for (int ii = 0; ii < 4; ++ii) {  // A: 64 rows x 32k, sc1 float2
                        int idx = tid + ii * 256;
                        int r = idx >> 4, c2 = idx & 15;
                        const float* arow = hbuf + ((size_t)r * LL + msel_s[r]) * DD;
                        float2 v = ldf2(arow + kbase + c2 * 2);
                        As[c2 * 2 + 0][r] = v.x;
                        As[c2 * 2 + 1][r] = v.y;
                    }
#pragma unroll
                    for (int ii = 0; ii < 2; ++ii) {  // B: 64 W-rows x 32k, cached
                        int idx = tid + ii * 256;
                        int r = idx >> 3, c4 = idx & 7;
                        int n = ntile * 64 + r;
                        const float* wrow = (n < GG)
                                                ? (comp_W + (size_t)n * (2 * DD))
                                                : (comp_W + (size_t)(n - GG) * (2 * DD) + DD);
                        float4 v = *(const float4*)(wrow + kbase + c4 * 4);
                        Bs[c4 * 4 + 0][r] = v.x;
                        Bs[c4 * 4 + 1][r] = v.y;
                        Bs[c4 * 4 + 2][r] = v.z;
                        Bs[c4 * 4 + 3][r] = v.w;
                    }
                    __syncthreads();
#pragma unroll
                    for (int k = 0; k < 32; ++k) {
                        float4 a = *(const float4*)&As[k][tm * 4];
                        float4 w = *(const float4*)&Bs[k][tn * 4];
                        float av[4] = {a.x, a.y, a.z, a.w};
                        float wv[4] = {w.x, w.y, w.z, w.w};
#pragma unroll
                        for (int y = 0; y < 4; ++y)
#pragma unroll
                            for (int x = 0; x < 4; ++x) acc[y][x] += av[y] * wv[x];
                    }
                    __syncthreads();
                }
#pragma unroll
                for (int y = 0; y < 4; ++y) {  // sc1 partial writes
                    int m = tm * 4 + y;
                    float* dst = part + (size_t)(kb * BB + m) * (2 * GG) + ntile * 64 + tn * 4;
                    stf2(dst + 0, acc[y][0], acc[y][1]);
                    stf2(dst + 2, acc[y][2], acc[y][3]);
                }
            }
            gbar(slots, gen, ++ep);
        }
    }

    if (amA) {
        __syncthreads();
        const int s0 = seq_l[0];  // slot 0 never shifts
        const int d = 2 * tid;
        float2 v = ldf2(hbuf + (size_t)(b * LL + s0) * DD + d);  // sc1 (rows were sc1-written)
        *(float2*)(out + (size_t)b * DD + d) = v;
    }
}

// ---------------------------------------------------------------------------
extern "C" void kernel_launch(void* const* d_in, const int* in_sizes, int n_in, void* d_out,
                              int out_size, void* d_ws, size_t ws_size, hipStream_t stream) {
    const float* inp = (const float*)d_in[0];
    const int* length = (const int*)d_in[1];
    const float* word_W = (const float*)d_in[2];
    const float* word_b = (const float*)d_in[3];
    const float* comp_W = (const float*)d_in[4];
    const float* comp_b = (const float*)d_in[5];
    const float* comp_q = (const float*)d_in[6];
    float* out = (float*)d_out;

    float* ws = (float*)d_ws;
    size_t off = 0;
    float* hbuf = ws + off;   off += (size_t)BB * LL * DD;
    float* cbuf = ws + off;   off += (size_t)BB * LL * DD;
    float* acache = ws + off; off += (size_t)BB * LL * GG;
    float* bcache = ws + off; off += (size_t)BB * LL * GG;
    float* part = ws + off;   off += (size_t)KS * BB * 2 * GG;
    float* scores = ws + off; off += 2048;
    int* msel = (int*)(ws + off); off += 64;
    int* bar = (int*)(ws + off);  off += NBLK + 64;
    (void)ws_size; (void)in_sizes; (void)n_in; (void)out_size;

    // zero barrier state (ws is poisoned 0xAA before every call)
    init_k<<<1, 256, 0, stream>>>(bar);

    // word projection: h,c = split(inp @ word_W.T + word_b)
    gemm_big<0><<<dim3(8, 12), 256, 0, stream>>>(inp, word_W, word_b, hbuf, cbuf);

    // a/b caches for all 1536 items
    gemm_big<1><<<dim3(40, 12), 256, 0, stream>>>(hbuf, comp_W, nullptr, acache, bcache);

    // persistent kernel: initial scores + all merge steps
    const int* a0 = length;
    float* a1 = hbuf; float* a2 = cbuf; float* a3 = acache; float* a4 = bcache;
    float* a5 = part; float* a6 = scores; int* a7 = msel;
    const float* a8 = comp_W; const float* a9 = comp_b; const float* a10 = comp_q;
    float* a11 = out; int* a12 = bar;
    void* args[] = {&a0, &a1, &a2, &a3, &a4, &a5, &a6, &a7, &a8, &a9, &a10, &a11, &a12};
    hipError_t err = hipLaunchCooperativeKernel(reinterpret_cast<void*>(loop_k), dim3(NBLK),
                                                dim3(256), args, 0, stream);
    (void)err;
}

// Round 7
// 986.225 us; speedup vs baseline: 3.3028x; 1.0361x over previous
//
#include <hip/hip_runtime.h>
#include <math.h>

// Problem constants
#define BB 64
#define LL 24
#define DD 512
#define GG 2560        // 5*H
#define NSTEP 23       // LL-1
#define NBLK 256       // cooperative grid (1 block/CU, proven resident)
#define NTILES 160     // phase-B n-tiles: 5120/32, full-K per tile (no partials)

__device__ __forceinline__ float sigm(float x) { return 1.0f / (1.0f + __expf(-x)); }

// ---------------------------------------------------------------------------
// Agent-scope (sc1) relaxed access helpers — cross-XCD coherent, NO cache
// maintenance (R5 lesson). Ordering via __syncthreads vmcnt drain + drains.
// ---------------------------------------------------------------------------
__device__ __forceinline__ void stf2(float* p, float a, float b) {
    union { float f[2]; unsigned long long u; } x;
    x.f[0] = a; x.f[1] = b;
    __hip_atomic_store((unsigned long long*)p, x.u, __ATOMIC_RELAXED, __HIP_MEMORY_SCOPE_AGENT);
}
__device__ __forceinline__ float2 ldf2(const float* p) {
    union { float f[2]; unsigned long long u; } x;
    x.u = __hip_atomic_load((unsigned long long*)p, __ATOMIC_RELAXED, __HIP_MEMORY_SCOPE_AGENT);
    return make_float2(x.f[0], x.f[1]);
}
__device__ __forceinline__ void stf(float* p, float v) {
    __hip_atomic_store(p, v, __ATOMIC_RELAXED, __HIP_MEMORY_SCOPE_AGENT);
}
__device__ __forceinline__ float ldf(const float* p) {
    return __hip_atomic_load((float*)p, __ATOMIC_RELAXED, __HIP_MEMORY_SCOPE_AGENT);
}
__device__ __forceinline__ void sti(int* p, int v) {
    __hip_atomic_store(p, v, __ATOMIC_RELAXED, __HIP_MEMORY_SCOPE_AGENT);
}
__device__ __forceinline__ int ldi(const int* p) {
    return __hip_atomic_load((int*)p, __ATOMIC_RELAXED, __HIP_MEMORY_SCOPE_AGENT);
}
__device__ __forceinline__ void drain_stores() {
    asm volatile("s_waitcnt vmcnt(0)" ::: "memory");
}

// ---------------------------------------------------------------------------
// Slot-array grid barrier, 8-way gen fan-out (32 spinners per gen cacheline).
// ---------------------------------------------------------------------------
__device__ __forceinline__ void gbar(int* __restrict__ slots, int* __restrict__ gen8,
                                     int target) {
    __syncthreads();  // drains each wave's outstanding vmem before s_barrier
    if (blockIdx.x == 0) {
        if (threadIdx.x < 64) {
            bool alldone = false;
            while (!alldone) {
                bool ok = true;
#pragma unroll
                for (int j = 0; j < NBLK / 64; ++j)
                    ok &= (ldi(&slots[threadIdx.x + j * 64]) >= target);
                alldone = __all(ok);
                if (!alldone) __builtin_amdgcn_s_sleep(2);
            }
        }
        __syncthreads();
        if (threadIdx.x < 8) { drain_stores(); sti(&gen8[threadIdx.x * 16], target); }
    } else {
        if (threadIdx.x == 0) {
            drain_stores();
            sti(&slots[blockIdx.x], target);
            while (ldi(&gen8[(blockIdx.x >> 5) * 16]) < target) __builtin_amdgcn_s_sleep(2);
        }
    }
    __syncthreads();
}

// ---------------------------------------------------------------------------
// init barrier state. slots[0] = INT_MAX (block 0 never stores its slot).
// ---------------------------------------------------------------------------
__global__ void init_k(int* __restrict__ bar) {
    int tid = threadIdx.x;
    if (tid < NBLK) bar[tid] = (tid == 0) ? 0x7FFFFFFF : 0;
    if (tid >= NBLK && tid < NBLK + 128) bar[tid] = 0;  // gen8 region
}

// ---------------------------------------------------------------------------
// fp32 GEMM, 64x128 tile (retiled from 128x128 for 2-4x more blocks).
// C[m][n] = sum_k A[m][k]*W[n][k] (+bias). Conflict-free LDS microtile.
// MODE 0 = WORD (W 1024x512 row-major, bias, out h|c split at n=512)
// MODE 1 = AB0  (W = comp_W halves at n=2560)
// ---------------------------------------------------------------------------
template <int MODE>
__global__ __launch_bounds__(256) void gemm64(const float* __restrict__ A,
                                              const float* __restrict__ Wt,
                                              const float* __restrict__ bias,
                                              float* __restrict__ O0,
                                              float* __restrict__ O1) {
    __shared__ float As[16][68];
    __shared__ float Bs[16][132];
    const int tid = threadIdx.x;
    const int n0 = blockIdx.x * 128;
    const int m0 = blockIdx.y * 64;
    const int tn = tid & 15;
    const int tm = tid >> 4;

    float acc[4][8];
#pragma unroll
    for (int y = 0; y < 4; ++y)
#pragma unroll
        for (int x = 0; x < 8; ++x) acc[y][x] = 0.f;

    for (int kt = 0; kt < 512; kt += 16) {
        {  // A: 64 rows x 16 k = 1024 floats, 1 float4/thread
            int r = tid >> 2, c4 = tid & 3;
            float4 v = *(const float4*)(A + (size_t)(m0 + r) * DD + kt + c4 * 4);
            As[c4 * 4 + 0][r] = v.x;
            As[c4 * 4 + 1][r] = v.y;
            As[c4 * 4 + 2][r] = v.z;
            As[c4 * 4 + 3][r] = v.w;
        }
#pragma unroll
        for (int ii = 0; ii < 2; ++ii) {  // B: 128 rows x 16 k
            int idx = tid + ii * 256;
            int r = idx >> 2, c4 = idx & 3;
            int n = n0 + r;
            const float* wrow;
            if constexpr (MODE == 0) {
                wrow = Wt + (size_t)n * DD;
            } else {
                wrow = (n < GG) ? (Wt + (size_t)n * (2 * DD))
                                : (Wt + (size_t)(n - GG) * (2 * DD) + DD);
            }
            float4 v = *(const float4*)(wrow + kt + c4 * 4);
            Bs[c4 * 4 + 0][r] = v.x;
            Bs[c4 * 4 + 1][r] = v.y;
            Bs[c4 * 4 + 2][r] = v.z;
            Bs[c4 * 4 + 3][r] = v.w;
        }
        __syncthreads();
#pragma unroll
        for (int k = 0; k < 16; ++k) {
            float4 a = *(const float4*)&As[k][tm * 4];
            float4 b0 = *(const float4*)&Bs[k][tn * 4];
            float4 b1 = *(const float4*)&Bs[k][64 + tn * 4];
            float av[4] = {a.x, a.y, a.z, a.w};
            float bv[8] = {b0.x, b0.y, b0.z, b0.w, b1.x, b1.y, b1.z, b1.w};
#pragma unroll
            for (int y = 0; y < 4; ++y)
#pragma unroll
                for (int x = 0; x < 8; ++x) acc[y][x] += av[y] * bv[x];
        }
        __syncthreads();
    }

#pragma unroll
    for (int y = 0; y < 4; ++y) {
        const int m = m0 + tm * 4 + y;
#pragma unroll
        for (int g = 0; g < 2; ++g) {
            int n = n0 + g * 64 + tn * 4;
            float4 v;
            v.x = acc[y][g * 4 + 0];
            v.y = acc[y][g * 4 + 1];
            v.z = acc[y][g * 4 + 2];
            v.w = acc[y][g * 4 + 3];
            float* dst;
            if constexpr (MODE == 0) {
                v.x += bias[n + 0];
                v.y += bias[n + 1];
                v.z += bias[n + 2];
                v.w += bias[n + 3];
                dst = (n < DD) ? (O0 + (size_t)m * DD + n) : (O1 + (size_t)m * DD + (n - DD));
            } else {
                dst = (n < GG) ? (O0 + (size_t)m * GG + n) : (O1 + (size_t)m * GG + (n - GG));
            }
            *(float4*)dst = v;
        }
    }
}

// ---------------------------------------------------------------------------
// pre-phase scorer (normal cached loads; operands from previous dispatches)
// ---------------------------------------------------------------------------
__device__ __forceinline__ float half_dot(const float* __restrict__ ar,
                                          const float* __restrict__ br,
                                          const float* __restrict__ cb,
                                          const float* __restrict__ cl,
                                          const float* __restrict__ cr,
                                          const float* __restrict__ q, int lane) {
    float part = 0.f;
#pragma unroll
    for (int d = lane; d < DD; d += 128) {
        float gi = ar[d] + br[d] + cb[d];
        float gfl = ar[DD + d] + br[DD + d] + cb[DD + d];
        float gfr = ar[2 * DD + d] + br[2 * DD + d] + cb[2 * DD + d];
        float gu = ar[3 * DD + d] + br[3 * DD + d] + cb[3 * DD + d];
        float go = ar[4 * DD + d] + br[4 * DD + d] + cb[4 * DD + d];
        float nc = cl[d] * sigm(gfl + 1.f) + cr[d] * sigm(gfr + 1.f) + tanhf(gu) * sigm(gi);
        part += sigm(go) * tanhf(nc) * q[d];
    }
#pragma unroll
    for (int off = 32; off; off >>= 1) part += __shfl_down(part, off);
    return part;
}

// ---------------------------------------------------------------------------
// sc1 gate pair: compute (nh, nc) for 2 consecutive dims d, d+1.
// a/b rows read coherent (phase-B written); c rows + consts normal.
// ---------------------------------------------------------------------------
__device__ __forceinline__ void gate2(const float* ar, const float* br,
                                      const float* __restrict__ cb,
                                      const float* __restrict__ cl,
                                      const float* __restrict__ cr, int d,
                                      float nh[2], float nc[2]) {
    float2 A0 = ldf2(ar + d),          B0 = ldf2(br + d);
    float2 A1 = ldf2(ar + DD + d),     B1 = ldf2(br + DD + d);
    float2 A2 = ldf2(ar + 2 * DD + d), B2 = ldf2(br + 2 * DD + d);
    float2 A3 = ldf2(ar + 3 * DD + d), B3 = ldf2(br + 3 * DD + d);
    float2 A4 = ldf2(ar + 4 * DD + d), B4 = ldf2(br + 4 * DD + d);
    float2 C0 = *(const float2*)(cb + d);
    float2 C1 = *(const float2*)(cb + DD + d);
    float2 C2 = *(const float2*)(cb + 2 * DD + d);
    float2 C3 = *(const float2*)(cb + 3 * DD + d);
    float2 C4 = *(const float2*)(cb + 4 * DD + d);
    float2 CL = *(const float2*)(cl + d);
    float2 CR = *(const float2*)(cr + d);
    float gi0 = A0.x + B0.x + C0.x, gi1 = A0.y + B0.y + C0.y;
    float gfl0 = A1.x + B1.x + C1.x, gfl1 = A1.y + B1.y + C1.y;
    float gfr0 = A2.x + B2.x + C2.x, gfr1 = A2.y + B2.y + C2.y;
    float gu0 = A3.x + B3.x + C3.x, gu1 = A3.y + B3.y + C3.y;
    float go0 = A4.x + B4.x + C4.x, go1 = A4.y + B4.y + C4.y;
    nc[0] = CL.x * sigm(gfl0 + 1.f) + CR.x * sigm(gfr0 + 1.f) + tanhf(gu0) * sigm(gi0);
    nc[1] = CL.y * sigm(gfl1 + 1.f) + CR.y * sigm(gfr1 + 1.f) + tanhf(gu1) * sigm(gi1);
    nh[0] = sigm(go0) * tanhf(nc[0]);
    nh[1] = sigm(go1) * tanhf(nc[1]);
}

// ---------------------------------------------------------------------------
// Persistent kernel: pre-scores + 23 merge steps.
// Phase A (blocks 0..63): rescore 2 affected candidates (sc1 a/b reads) ->
//   argmax -> merge gates -> hout (private) + hm[i] (sc1 broadcast) + msel.
// Phase B (blocks 0..159): n-tile 32, FULL K=512, A-operand = hm[i] via
//   NORMAL float4 loads (fresh addresses per step -> correct + L2-broadcast),
//   W from L2 (stable block->XCD residency), outputs stf2 to a/b caches.
// ---------------------------------------------------------------------------
__global__ __launch_bounds__(256, 2) void loop_k(
    const int* __restrict__ length, float* __restrict__ cbuf, float* __restrict__ acache,
    float* __restrict__ bcache, float* __restrict__ hm, float* __restrict__ hout,
    float* __restrict__ scores_g, int* __restrict__ msel, const float* __restrict__ comp_W,
    const float* __restrict__ compb, const float* __restrict__ q, float* __restrict__ out,
    int* __restrict__ bar) {
    __shared__ float As[128][68];   // phase-B A chunk (k-major, padded)
    __shared__ float Bs[128][36];   // phase-B W chunk
    __shared__ float red_s[4];
    __shared__ float sc_l[32];
    __shared__ int seq_l[32];
    __shared__ int k_sh;
    __shared__ int msel_s[BB];

    const int tid = threadIdx.x;
    const int bid = blockIdx.x;
    const int b = bid;
    const bool amA = bid < BB;
    const int half = tid >> 7;
    const int lane7 = tid & 127;

    int* slots = bar;
    int* gen8 = bar + NBLK;

    int maxlen = 0;
    for (int j = 0; j < BB; ++j) maxlen = max(maxlen, length[j]);
    int lenb = 0, kp = 0;
    if (amA) lenb = length[b];

    // ---- pre-phase: 23x64 initial candidate scores (512 half-block tasks) ---
    for (int it = 0; it < 3; ++it) {
        int c = it * (2 * NBLK) + bid * 2 + half;
        bool valid = c < BB * NSTEP;
        float w = 0.f;
        if (valid) {
            int cb_ = c / NSTEP, cp = c % NSTEP;
            w = half_dot(acache + (size_t)(cb_ * LL + cp) * GG,
                         bcache + (size_t)(cb_ * LL + cp + 1) * GG, compb,
                         cbuf + (size_t)(cb_ * LL + cp) * DD,
                         cbuf + (size_t)(cb_ * LL + cp + 1) * DD, q, lane7);
        }
        if ((tid & 63) == 0) red_s[tid >> 6] = w;
        __syncthreads();
        if ((tid == 0 || tid == 128) && valid) {
            int base = (tid >> 6);
            stf(&scores_g[c], red_s[base] + red_s[base + 1]);
        }
        __syncthreads();
    }
    int ep = 0;
    gbar(slots, gen8, ++ep);

    if (amA) {
        if (tid < NSTEP) sc_l[tid] = ldf(&scores_g[b * NSTEP + tid]);
        if (tid < LL) seq_l[tid] = tid;
    }
    __syncthreads();

    const int imax = min(NSTEP, maxlen - 1);
    for (int i = 0; i < imax; ++i) {
        // ---------------- phase A (blocks 0..63) ----------------
        if (amA) {
            const int ncand = NSTEP - i;
            if (i > 0 && i < lenb) {
                // rescore <=2 affected candidates, half-block each, sc1 a/b
                int p = (tid < 128) ? (kp - 1) : kp;
                bool valid = (p >= 0) && (p < ncand);
                float w = 0.f;
                if (valid) {
                    int sl = seq_l[p], sr = seq_l[p + 1];
                    const float* ar = acache + (size_t)(b * LL + sl) * GG;
                    const float* br = bcache + (size_t)(b * LL + sr) * GG;
                    const float* cl = cbuf + (size_t)(b * LL + sl) * DD;
                    const float* cr = cbuf + (size_t)(b * LL + sr) * DD;
#pragma unroll
                    for (int pass = 0; pass < 2; ++pass) {
                        int d = pass * 256 + lane7 * 2;
                        float nh[2], nc[2];
                        gate2(ar, br, compb, cl, cr, d, nh, nc);
                        float2 Q = *(const float2*)(q + d);
                        w += nh[0] * Q.x + nh[1] * Q.y;
                    }
#pragma unroll
                    for (int off = 32; off; off >>= 1) w += __shfl_down(w, off);
                }
                if ((tid & 63) == 0) red_s[tid >> 6] = w;
                __syncthreads();
                if (tid == 0) {
                    if (kp - 1 >= 0) sc_l[kp - 1] = red_s[0] + red_s[1];
                    if (kp < ncand) sc_l[kp] = red_s[2] + red_s[3];
                }
                __syncthreads();
            }
            if (i + 1 < lenb) {
                if (tid == 0) {
                    const int vmax = lenb - i - 2;
                    int k = 0;
                    float best = sc_l[0];
                    for (int pp = 1; pp <= vmax; ++pp)
                        if (sc_l[pp] > best) { best = sc_l[pp]; k = pp; }
                    k_sh = k;
                }
                __syncthreads();
                const int k = k_sh;
                const int sl = seq_l[k], sr = seq_l[k + 1];
                const float* ar = acache + (size_t)(b * LL + sl) * GG;
                const float* br = bcache + (size_t)(b * LL + sr) * GG;
                const float* cl = cbuf + (size_t)(b * LL + sl) * DD;
                const float* cr = cbuf + (size_t)(b * LL + sr) * DD;
                {
                    const int d = 2 * tid;
                    float nh[2], nc[2];
                    gate2(ar, br, compb, cl, cr, d, nh, nc);
                    *(float2*)(cbuf + (size_t)(b * LL + sl) * DD + d) =
                        make_float2(nc[0], nc[1]);
                    *(float2*)(hout + (size_t)b * DD + d) = make_float2(nh[0], nh[1]);
                    stf2(hm + ((size_t)i * BB + b) * DD + d, nh[0], nh[1]);
                }
                float sv = (tid + 1 < ncand) ? sc_l[tid + 1] : 0.f;
                int qv = (tid + 1 < LL - i) ? seq_l[tid + 1] : 0;
                __syncthreads();
                if (tid >= k + 1 && tid <= ncand - 2) sc_l[tid] = sv;
                if (tid >= k + 1 && tid <= LL - i - 2) seq_l[tid] = qv;
                if (tid == 0) sti(&msel[b], sl);
                kp = k;
            } else {
                // done batch: keep hm[i] valid (re-broadcast last h; benign rewrite)
                const int d = 2 * tid;
                float2 v = *(const float2*)(hout + (size_t)b * DD + d);
                stf2(hm + ((size_t)i * BB + b) * DD + d, v.x, v.y);
            }
        }
        // ---------------- phase B (blocks 0..159) ----------------
        if (i < imax - 1) {
            gbar(slots, gen8, ++ep);
            if (tid < BB) msel_s[tid] = ldi(&msel[tid]);
            __syncthreads();
            if (bid < NTILES) {
                const int n0 = bid * 32;
                const int tn = tid & 15, tm = tid >> 4;
                const float* hmi = hm + (size_t)i * BB * DD;
                const int r_ = tid >> 2, cg = tid & 3;  // A-load role
                const int nl = tid >> 3, kg = tid & 7;  // W-load role
                const float* arow = hmi + (size_t)r_ * DD;
                const float* wrow;
                {
                    int n = n0 + nl;
                    wrow = (n < GG) ? (comp_W + (size_t)n * (2 * DD))
                                    : (comp_W + (size_t)(n - GG) * (2 * DD) + DD);
                }
                float acc[4][2];
#pragma unroll
                for (int y = 0; y < 4; ++y) { acc[y][0] = 0.f; acc[y][1] = 0.f; }
                float4 ra[8], rw[4];
#pragma unroll
                for (int j = 0; j < 8; ++j) ra[j] = *(const float4*)(arow + cg * 32 + j * 4);
#pragma unroll
                for (int j = 0; j < 4; ++j) rw[j] = *(const float4*)(wrow + kg * 16 + j * 4);
#pragma unroll
                for (int c = 0; c < 4; ++c) {
                    __syncthreads();
#pragma unroll
                    for (int j = 0; j < 8; ++j) {
                        int kl = cg * 32 + j * 4;
                        As[kl + 0][r_] = ra[j].x;
                        As[kl + 1][r_] = ra[j].y;
                        As[kl + 2][r_] = ra[j].z;
                        As[kl + 3][r_] = ra[j].w;
                    }
#pragma unroll
                    for (int j = 0; j < 4; ++j) {
                        int kl = kg * 16 + j * 4;
                        Bs[kl + 0][nl] = rw[j].x;
                        Bs[kl + 1][nl] = rw[j].y;
                        Bs[kl + 2][nl] = rw[j].z;
                        Bs[kl + 3][nl] = rw[j].w;
                    }
                    if (c < 3) {  // prefetch next chunk during compute
                        int kb = (c + 1) * 128;
#pragma unroll
                        for (int j = 0; j < 8; ++j)
                            ra[j] = *(const float4*)(arow + kb + cg * 32 + j * 4);
#pragma unroll
                        for (int j = 0; j < 4; ++j)
                            rw[j] = *(const float4*)(wrow + kb + kg * 16 + j * 4);
                    }
                    __syncthreads();
#pragma unroll 8
                    for (int k = 0; k < 128; ++k) {
                        float4 a = *(const float4*)&As[k][tm * 4];
                        float2 w = *(const float2*)&Bs[k][tn * 2];
                        acc[0][0] += a.x * w.x; acc[0][1] += a.x * w.y;
                        acc[1][0] += a.y * w.x; acc[1][1] += a.y * w.y;
                        acc[2][0] += a.z * w.x; acc[2][1] += a.z * w.y;
                        acc[3][0] += a.w * w.x; acc[3][1] += a.w * w.y;
                    }
                }
                const int n = n0 + tn * 2;
#pragma unroll
                for (int y = 0; y < 4; ++y) {
                    int m = tm * 4 + y;
                    size_t row = (size_t)(m * LL + msel_s[m]);
                    if (n < GG) stf2(acache + row * GG + n, acc[y][0], acc[y][1]);
                    else stf2(bcache + row * GG + (n - GG), acc[y][0], acc[y][1]);
                }
            }
            gbar(slots, gen8, ++ep);
        }
    }

    if (amA) {  // final output = last merged h (owner-private hout)
        const int d = 2 * tid;
        *(float2*)(out + (size_t)b * DD + d) = *(const float2*)(hout + (size_t)b * DD + d);
    }
}

// ---------------------------------------------------------------------------
extern "C" void kernel_launch(void* const* d_in, const int* in_sizes, int n_in, void* d_out,
                              int out_size, void* d_ws, size_t ws_size, hipStream_t stream) {
    const float* inp = (const float*)d_in[0];
    const int* length = (const int*)d_in[1];
    const float* word_W = (const float*)d_in[2];
    const float* word_b = (const float*)d_in[3];
    const float* comp_W = (const float*)d_in[4];
    const float* comp_b = (const float*)d_in[5];
    const float* comp_q = (const float*)d_in[6];
    float* out = (float*)d_out;

    float* ws = (float*)d_ws;
    size_t off = 0;
    float* hbuf = ws + off;   off += (size_t)BB * LL * DD;
    float* cbuf = ws + off;   off += (size_t)BB * LL * DD;
    float* acache = ws + off; off += (size_t)BB * LL * GG;
    float* bcache = ws + off; off += (size_t)BB * LL * GG;
    float* hm = ws + off;     off += (size_t)NSTEP * BB * DD;
    float* hout = ws + off;   off += (size_t)BB * DD;
    float* scores = ws + off; off += 2048;
    int* msel = (int*)(ws + off); off += 64;
    int* bar = (int*)(ws + off);  off += NBLK + 128;
    (void)ws_size; (void)in_sizes; (void)n_in; (void)out_size;

    init_k<<<1, 1024, 0, stream>>>(bar);

    // word projection: h,c = split(inp @ word_W.T + word_b)   (192 blocks)
    gemm64<0><<<dim3(8, 24), 256, 0, stream>>>(inp, word_W, word_b, hbuf, cbuf);

    // a/b caches for all 1536 items                            (960 blocks)
    gemm64<1><<<dim3(40, 24), 256, 0, stream>>>(hbuf, comp_W, nullptr, acache, bcache);

    // persistent kernel: pre-scores + all merge steps
    const int* a0 = length;
    float* a1 = cbuf; float* a2 = acache; float* a3 = bcache; float* a4 = hm;
    float* a5 = hout; float* a6 = scores; int* a7 = msel;
    const float* a8 = comp_W; const float* a9 = comp_b; const float* a10 = comp_q;
    float* a11 = out; int* a12 = bar;
    void* args[] = {&a0, &a1, &a2, &a3, &a4, &a5, &a6, &a7, &a8, &a9, &a10, &a11, &a12};
    hipError_t err = hipLaunchCooperativeKernel(reinterpret_cast<void*>(loop_k), dim3(NBLK),
                                                dim3(256), args, 0, stream);
    (void)err;
}